// Round 5
// baseline (276.879 us; speedup 1.0000x reference)
//
#include <hip/hip_runtime.h>

#define HH 352
#define WW 1216
#define NB 4
#define HWSZ (HH * WW)      // 428032 pixels per plane
#define WQ 304              // quads per row
#define NQ (NB * HH * WQ)   // 428032 thread-quads (softmax)

typedef _Float16 half8 __attribute__((ext_vector_type(8)));

// kern ws layout: [NB][9][HWSZ][2] fp16, innermost pair = (k1,k2) premultiplied
// by fuse. One 16B load per (quad, tap) serves 4 px x both kernels.

// ---------------------------------------------------------------------------
// Softmax(9ch) for both guided tensors, premultiplied by fuse, interleaved
// fp16 store. ALL 18 plane loads hoisted before any use (in-place exp) to
// maximize loads-in-flight; launch_bounds(256,2) -> VGPR cap 256.
// ---------------------------------------------------------------------------
__global__ __launch_bounds__(256, 2) void softmax_premul_kernel(
    const float* __restrict__ g1, const float* __restrict__ g2,
    const float* __restrict__ fuse, _Float16* __restrict__ ko) {
    int q = blockIdx.x * 256 + threadIdx.x;
    if (q >= NQ) return;
    int b   = q / (HH * WQ);
    int rem = q - b * (HH * WQ);
    long gbase = (long)b * 9 * HWSZ + (long)rem * 4;
    long fbase = (long)b * 2 * HWSZ + (long)rem * 4;

    float4 t[18];
#pragma unroll
    for (int k = 0; k < 9; k++) t[k]     = *(const float4*)(g1 + gbase + (long)k * HWSZ);
#pragma unroll
    for (int k = 0; k < 9; k++) t[9 + k] = *(const float4*)(g2 + gbase + (long)k * HWSZ);
    float4 f1 = *(const float4*)(fuse + fbase);
    float4 f2 = *(const float4*)(fuse + fbase + HWSZ);

    float s1[4] = {0.f, 0.f, 0.f, 0.f}, s2[4] = {0.f, 0.f, 0.f, 0.f};
#pragma unroll
    for (int k = 0; k < 9; k++) {
        t[k].x = __expf(t[k].x); s1[0] += t[k].x;
        t[k].y = __expf(t[k].y); s1[1] += t[k].y;
        t[k].z = __expf(t[k].z); s1[2] += t[k].z;
        t[k].w = __expf(t[k].w); s1[3] += t[k].w;
    }
#pragma unroll
    for (int k = 9; k < 18; k++) {
        t[k].x = __expf(t[k].x); s2[0] += t[k].x;
        t[k].y = __expf(t[k].y); s2[1] += t[k].y;
        t[k].z = __expf(t[k].z); s2[2] += t[k].z;
        t[k].w = __expf(t[k].w); s2[3] += t[k].w;
    }
    float r1[4], r2[4];
    r1[0] = f1.x / s1[0]; r1[1] = f1.y / s1[1]; r1[2] = f1.z / s1[2]; r1[3] = f1.w / s1[3];
    r2[0] = f2.x / s2[0]; r2[1] = f2.y / s2[1]; r2[2] = f2.z / s2[2]; r2[3] = f2.w / s2[3];

    long obase = ((long)b * 9 * HWSZ + (long)rem * 4) * 2;
#pragma unroll
    for (int k = 0; k < 9; k++) {
        half8 o;
        o[0] = (_Float16)(t[k].x * r1[0]); o[1] = (_Float16)(t[9 + k].x * r2[0]);
        o[2] = (_Float16)(t[k].y * r1[1]); o[3] = (_Float16)(t[9 + k].y * r2[1]);
        o[4] = (_Float16)(t[k].z * r1[2]); o[5] = (_Float16)(t[9 + k].z * r2[2]);
        o[6] = (_Float16)(t[k].w * r1[3]); o[7] = (_Float16)(t[9 + k].w * r2[3]);
        *(half8*)(ko + obase + (long)k * HWSZ * 2) = o;
    }
}

// ---------------------------------------------------------------------------
// TWO fused propagation steps. Core tile: 8 rows x 304 px (76 quads) — tiles
// the image exactly (44 x 4 tiles x 4 batches = 704 blocks, 512 thr each).
//   region1 (intermediate x1): 12 rows x 78 quads = 936 quads
//   x0 staged: 16 rows x 80 quads in LDS
// Each thread owns quads {tid, tid+512} of region1, loads their kern ONCE
// into registers (reused by both steps; out-of-image quads get kern=0 so
// x1=0 = reference zero-padding). Step A writes x1 to LDS; step B computes
// the core subset from x1 with the same register kern and stores to global.
// Kern traffic per 2 steps: 936/1216 = 0.77x of ONE full pass (vs 2x unfused).
// ---------------------------------------------------------------------------
#define CTH 8
#define CTQ 76
#define R1H 12
#define R1Q 78
#define X0H 16
#define X0Q 80
#define NREG (R1H * R1Q)    // 936

__global__ __launch_bounds__(512, 2) void prop2_kernel(
    const _Float16* __restrict__ kk,
    const float* __restrict__ xin, float* __restrict__ xout) {
    __shared__ float x0s[X0H][X0Q * 4];   // 20.5 KB
    __shared__ float x1s[R1H][R1Q * 4];   // 15.0 KB

    int tid  = threadIdx.x;
    int bidx = blockIdx.x;
    int tX = bidx & 3;
    int rr = bidx >> 2;
    int tY = rr % 44;
    int b  = rr / 44;
    int q0 = tX * CTQ;
    int h0 = tY * CTH;
    const float* xb = xin + (long)b * HWSZ;

    // ---- kern loads for owned region1 quads (long-latency, issue first) ----
    half8 kv[2][9];
    int own_r[2], own_c[2];
    bool own_v[2];
#pragma unroll
    for (int o = 0; o < 2; o++) {
        int idx = tid + o * 512;
        bool active = idx < NREG;
        int r = idx / R1Q;
        int c = idx - r * R1Q;
        own_r[o] = r; own_c[o] = c;
        int h  = h0 - 2 + r;
        int qg = q0 - 1 + c;
        bool valid = active && (h >= 0) && (h < HH) && (qg >= 0) && (qg < WQ);
        own_v[o] = active;
        long kb = ((long)b * 9 * HWSZ + (long)h * WW + qg * 4) * 2;
#pragma unroll
        for (int k = 0; k < 9; k++) {
            half8 z = {};
            kv[o][k] = valid ? *(const half8*)(kk + kb + (long)k * HWSZ * 2) : z;
        }
    }

    // ---- stage x0 (16 x 80 quads, zero-padded) ----
    for (int i = tid; i < X0H * X0Q; i += 512) {
        int r = i / X0Q;
        int c = i - r * X0Q;
        int h  = h0 - 4 + r;
        int qg = q0 - 2 + c;
        float4 v = make_float4(0.f, 0.f, 0.f, 0.f);
        if (h >= 0 && h < HH && qg >= 0 && qg < WQ)
            v = *(const float4*)(xb + (long)h * WW + qg * 4);
        *(float4*)&x0s[r][c * 4] = v;
    }
    __syncthreads();

    // ---- step A: x1 over region1, into LDS ----
#pragma unroll
    for (int o = 0; o < 2; o++) {
        if (!own_v[o]) continue;
        int r = own_r[o], c = own_c[o];
        float rb[5][8];
#pragma unroll
        for (int y = 0; y < 5; y++) {
            const float* p = &x0s[r + y][4 * c + 2];
            float2 a = *(const float2*)(p);
            float4 m = *(const float4*)(p + 2);
            float2 z = *(const float2*)(p + 6);
            rb[y][0] = a.x; rb[y][1] = a.y;
            rb[y][2] = m.x; rb[y][3] = m.y; rb[y][4] = m.z; rb[y][5] = m.w;
            rb[y][6] = z.x; rb[y][7] = z.y;
        }
        float ov[4] = {0.f, 0.f, 0.f, 0.f};
#pragma unroll
        for (int ky = 0; ky < 3; ky++)
#pragma unroll
            for (int kx = 0; kx < 3; kx++) {
                int k = ky * 3 + kx;
#pragma unroll
                for (int j = 0; j < 4; j++) {
                    ov[j] = fmaf((float)kv[o][k][2 * j],     rb[ky + 1][j + 1 + kx], ov[j]);
                    ov[j] = fmaf((float)kv[o][k][2 * j + 1], rb[2 * ky][j + 2 * kx], ov[j]);
                }
            }
        *(float4*)&x1s[r][c * 4] = make_float4(ov[0], ov[1], ov[2], ov[3]);
    }
    __syncthreads();

    // ---- step B: x2 over core subset of owned quads, same register kern ----
#pragma unroll
    for (int o = 0; o < 2; o++) {
        int r = own_r[o], c = own_c[o];
        if (!own_v[o] || r < 2 || r >= 10 || c < 1 || c >= 77) continue;
        float rb[5][8];
#pragma unroll
        for (int y = 0; y < 5; y++) {
            const float* p = &x1s[r - 2 + y][4 * c - 2];
            float2 a = *(const float2*)(p);
            float4 m = *(const float4*)(p + 2);
            float2 z = *(const float2*)(p + 6);
            rb[y][0] = a.x; rb[y][1] = a.y;
            rb[y][2] = m.x; rb[y][3] = m.y; rb[y][4] = m.z; rb[y][5] = m.w;
            rb[y][6] = z.x; rb[y][7] = z.y;
        }
        float ov[4] = {0.f, 0.f, 0.f, 0.f};
#pragma unroll
        for (int ky = 0; ky < 3; ky++)
#pragma unroll
            for (int kx = 0; kx < 3; kx++) {
                int k = ky * 3 + kx;
#pragma unroll
                for (int j = 0; j < 4; j++) {
                    ov[j] = fmaf((float)kv[o][k][2 * j],     rb[ky + 1][j + 1 + kx], ov[j]);
                    ov[j] = fmaf((float)kv[o][k][2 * j + 1], rb[2 * ky][j + 2 * kx], ov[j]);
                }
            }
        int h  = h0 - 2 + r;
        int qg = q0 - 1 + c;
        *(float4*)(xout + (long)b * HWSZ + (long)h * WW + qg * 4) =
            make_float4(ov[0], ov[1], ov[2], ov[3]);
    }
}

extern "C" void kernel_launch(void* const* d_in, const int* in_sizes, int n_in,
                              void* d_out, int out_size, void* d_ws, size_t ws_size,
                              hipStream_t stream) {
    const float* g1   = (const float*)d_in[0];
    const float* g2   = (const float*)d_in[1];
    const float* fuse = (const float*)d_in[2];
    const float* x    = (const float*)d_in[3];
    float* out = (float*)d_out;

    _Float16* kk = (_Float16*)d_ws;
    float* bufA  = (float*)(kk + (size_t)NB * 9 * HWSZ * 2);

    int sm_blocks = (NQ + 255) / 256;
    softmax_premul_kernel<<<sm_blocks, 256, 0, stream>>>(g1, g2, fuse, kk);

    int pr_blocks = NB * 44 * 4;   // 704
    prop2_kernel<<<pr_blocks, 512, 0, stream>>>(kk, x,    bufA);  // steps 1-2
    prop2_kernel<<<pr_blocks, 512, 0, stream>>>(kk, bufA, out);   // steps 3-4
    prop2_kernel<<<pr_blocks, 512, 0, stream>>>(kk, out,  bufA);  // steps 5-6
    prop2_kernel<<<pr_blocks, 512, 0, stream>>>(kk, bufA, out);   // steps 7-8
}